// Round 15
// baseline (334.716 us; speedup 1.0000x reference)
//
#include <hip/hip_runtime.h>
#include <hip/hip_bf16.h>

#define NN 207
#define DD 128
#define LL 4
#define BB 16
#define ROWS (BB*NN)   // 3312
#define RB 8
#define LBLK (ROWS/RB) // 414
#define EPSV 1e-5f
#define SLOPE 0.2f
#define GT4B (32*208*4) // floats per batch in packed-transposed gs

#define BFBITS 0x3F803F80u

// ---------- dtype-flexible load ----------
template<bool BF>
__device__ __forceinline__ float ldin(const void* p, int i) {
    if (BF) {
        unsigned short u = ((const unsigned short*)p)[i];
        return __uint_as_float(((unsigned)u) << 16);
    } else {
        return ((const float*)p)[i];
    }
}

// load float4 worth (4 elems) at float4-index q from a (possibly bf16) array
template<bool BF>
__device__ __forceinline__ float4 ld4(const void* p, int q4) {
    if (BF) {
        uint2 u = ((const uint2*)p)[q4];
        float4 r;
        r.x = __uint_as_float(u.x << 16);
        r.y = __uint_as_float(u.x & 0xFFFF0000u);
        r.z = __uint_as_float(u.y << 16);
        r.w = __uint_as_float(u.y & 0xFFFF0000u);
        return r;
    } else {
        return ((const float4*)p)[q4];
    }
}

// load 32 consecutive weight elements (base multiple of 8) into f32 regs
template<bool BF>
__device__ __forceinline__ void ldw32(const void* W, int base, float* w) {
    if (BF) {
        const uint4* p = (const uint4*)((const unsigned short*)W + base);
#pragma unroll
        for (int q = 0; q < 4; q++) {
            uint4 u = p[q];
            w[q*8+0] = __uint_as_float(u.x << 16);
            w[q*8+1] = __uint_as_float(u.x & 0xFFFF0000u);
            w[q*8+2] = __uint_as_float(u.y << 16);
            w[q*8+3] = __uint_as_float(u.y & 0xFFFF0000u);
            w[q*8+4] = __uint_as_float(u.z << 16);
            w[q*8+5] = __uint_as_float(u.z & 0xFFFF0000u);
            w[q*8+6] = __uint_as_float(u.w << 16);
            w[q*8+7] = __uint_as_float(u.w & 0xFFFF0000u);
        }
    } else {
        const float4* p = (const float4*)((const float*)W + base);
#pragma unroll
        for (int q = 0; q < 8; q++) {
            float4 u = p[q];
            w[q*4+0] = u.x; w[q*4+1] = u.y; w[q*4+2] = u.z; w[q*4+3] = u.w;
        }
    }
}

// dot of one weight row with sh[0..127] (k_et only)
template<bool BF>
__device__ __forceinline__ float rowdot(const void* W, int rowbase, const float* sh) {
    float acc = 0.f;
    if (BF) {
        const uint4* p = (const uint4*)((const unsigned short*)W + rowbase);
#pragma unroll
        for (int q = 0; q < DD / 8; q++) {
            uint4 u = p[q];
            const float* s = sh + q * 8;
            acc += __uint_as_float(u.x << 16)        * s[0];
            acc += __uint_as_float(u.x & 0xFFFF0000u) * s[1];
            acc += __uint_as_float(u.y << 16)        * s[2];
            acc += __uint_as_float(u.y & 0xFFFF0000u) * s[3];
            acc += __uint_as_float(u.z << 16)        * s[4];
            acc += __uint_as_float(u.z & 0xFFFF0000u) * s[5];
            acc += __uint_as_float(u.w << 16)        * s[6];
            acc += __uint_as_float(u.w & 0xFFFF0000u) * s[7];
        }
    } else {
        const float4* p = (const float4*)((const float*)W + rowbase);
#pragma unroll
        for (int q = 0; q < DD / 4; q++) {
            float4 u = p[q];
            const float* s = sh + q * 4;
            acc += u.x * s[0]; acc += u.y * s[1]; acc += u.z * s[2]; acc += u.w * s[3];
        }
    }
    return acc;
}

// ---------- edge tables: et[l][c12][d] ----------
template<bool BF>
__device__ void et_body(float* sh, const void* emb, const void* We, float* et) {
    int l = blockIdx.x / 12, c = blockIdx.x % 12, d = threadIdx.x;
    sh[d] = ldin<BF>(emb, c * DD + d);
    __syncthreads();
    et[(l * 12 + c) * DD + d] = rowdot<BF>(We, l * DD * DD + d * DD, sh);
}
__global__ void k_et(const unsigned* bits, const void* emb, const void* We, float* et) {
    __shared__ __align__(16) float smem[DD];
    if (bits[0] == BFBITS) et_body<true>(smem, emb, We, et);
    else                   et_body<false>(smem, emb, We, et);
}

// ---------- fused: [optional mlp1] -> linear + LN (+ReLU+res) -> h,
//            then next gs/gd/gs_t4 OR output head ----------
// smem: sh[RB*DD] | so[RB*132] | stats[16] | s_gs[RB*128] (s_x aliases s_gs)
#define LING_SMEM (RB*DD + RB*132 + 16 + RB*128)
template<bool BF>
__device__ void linG_body(float* smem, int hasPre, int epi, int hasNext,
                          const float* __restrict__ in,
                          const void* xin, const void* W1, const void* b1,
                          const void* g1, const void* bv1,
                          const void* W, int wOff,
                          const void* bias, const void* g, const void* bv, int dOff,
                          const void* Wl, const void* bl, const void* Wr, const void* br,
                          int nwOff, int nbOff,
                          float* __restrict__ h, float* __restrict__ gs,
                          float* __restrict__ gd, float* __restrict__ gs_t4,
                          const void* oW, const void* ob, void* out) {
    float* sh    = smem;
    float* so    = sh + RB * DD;
    float* stats = so + RB * 132;
    float* s_gs  = stats + 16;
    float* s_x   = s_gs;                 // alias (only used when hasPre, before s_gs)
    int r0 = blockIdx.x * RB;
    int t = threadIdx.x, d = t & 127, half = t >> 7;
    int rr2 = t >> 5, l32 = t & 31;

    if (hasPre) {
        // ---- inline mlp1: Linear(6->128) + LN1 + ReLU -> sh ----
        if (t < RB * 6) s_x[t] = ldin<BF>(xin, r0 * 6 + t);
        __syncthreads();
        if (half == 0) {
            float w6[6];
#pragma unroll
            for (int k = 0; k < 6; k++) w6[k] = ldin<BF>(W1, d * 6 + k);
            float b0p = ldin<BF>(b1, d);
#pragma unroll
            for (int rr = 0; rr < RB; rr++) {
                float a = b0p;
#pragma unroll
                for (int k = 0; k < 6; k++) a += w6[k] * s_x[rr * 6 + k];
                so[rr * 132 + d] = a;
            }
        }
        __syncthreads();
        float s = 0.f, sq = 0.f;
#pragma unroll
        for (int k = 0; k < 4; k++) { float v = so[rr2 * 132 + l32 + 32 * k]; s += v; sq += v * v; }
        s += __shfl_xor(s, 1); s += __shfl_xor(s, 2); s += __shfl_xor(s, 4);
        s += __shfl_xor(s, 8); s += __shfl_xor(s, 16);
        sq += __shfl_xor(sq, 1); sq += __shfl_xor(sq, 2); sq += __shfl_xor(sq, 4);
        sq += __shfl_xor(sq, 8); sq += __shfl_xor(sq, 16);
        if (l32 == 0) {
            float mean = s * (1.f / DD);
            float var = sq * (1.f / DD) - mean * mean;
            stats[rr2 * 2] = mean; stats[rr2 * 2 + 1] = rsqrtf(var + EPSV);
        }
        __syncthreads();
        float gvp = ldin<BF>(g1, d), bbp = ldin<BF>(bv1, d);
#pragma unroll
        for (int rr = 0; rr < 4; rr++) {
            int row = half * 4 + rr;
            float v = (so[row * 132 + d] - stats[row * 2]) * stats[row * 2 + 1] * gvp + bbp;
            sh[row * DD + d] = fmaxf(v, 0.f);
        }
        __syncthreads();
    } else {
        // ---- stage input rows into LDS (coalesced float4) ----
        ((float4*)sh)[t] = ((const float4*)(in + (size_t)r0 * DD))[t];
        __syncthreads();
    }

    // ---- phase A: projection linear (rows half*4..half*4+3) ----
    float acc[4];
    float b0 = ldin<BF>(bias, dOff + d);
#pragma unroll
    for (int rr = 0; rr < 4; rr++) acc[rr] = b0;
#pragma unroll
    for (int c = 0; c < 4; c++) {
        float w[32];
        ldw32<BF>(W, wOff + d * DD + c * 32, w);
#pragma unroll
        for (int rr = 0; rr < 4; rr++) {
            const float* s = sh + (half * 4 + rr) * DD + c * 32;
            float a = acc[rr];
#pragma unroll
            for (int k = 0; k < 32; k++) a += s[k] * w[k];
            acc[rr] = a;
        }
    }
    __syncthreads();   // so may be re-written below; prior reads done
#pragma unroll
    for (int rr = 0; rr < 4; rr++) so[(half * 4 + rr) * 132 + d] = acc[rr];
    __syncthreads();
    // ---- LN stats (8 rows x 32 lanes) ----
    {
        float s = 0.f, sq = 0.f;
#pragma unroll
        for (int k = 0; k < 4; k++) { float v = so[rr2 * 132 + l32 + 32 * k]; s += v; sq += v * v; }
        s += __shfl_xor(s, 1); s += __shfl_xor(s, 2); s += __shfl_xor(s, 4);
        s += __shfl_xor(s, 8); s += __shfl_xor(s, 16);
        sq += __shfl_xor(sq, 1); sq += __shfl_xor(sq, 2); sq += __shfl_xor(sq, 4);
        sq += __shfl_xor(sq, 8); sq += __shfl_xor(sq, 16);
        if (l32 == 0) {
            float mean = s * (1.f / DD);
            float var = sq * (1.f / DD) - mean * mean;
            stats[rr2 * 2] = mean; stats[rr2 * 2 + 1] = rsqrtf(var + EPSV);
        }
    }
    __syncthreads();
    // ---- epilogue: h_new -> global h AND into sh ----
    float gv = ldin<BF>(g, dOff + d), bb = ldin<BF>(bv, dOff + d);
#pragma unroll
    for (int rr = 0; rr < 4; rr++) {
        int row = half * 4 + rr;
        int rg = r0 + row;
        float v = (so[row * 132 + d] - stats[row * 2]) * stats[row * 2 + 1] * gv + bb;
        float hn;
        if (epi) hn = h[(size_t)rg * DD + d] + fmaxf(v, 0.f);
        else     hn = v;
        h[(size_t)rg * DD + d] = hn;
        sh[row * DD + d] = hn;
    }
    __syncthreads();
    if (!hasNext) {
        // ---- output head ----
        float s0 = 0.f, s1 = 0.f;
#pragma unroll
        for (int k = 0; k < 4; k++) {
            int dd = l32 + 32 * k;
            float hv = sh[rr2 * DD + dd];
            s0 += hv * ldin<BF>(oW, dd);
            s1 += hv * ldin<BF>(oW, DD + dd);
        }
        s0 += __shfl_xor(s0, 1); s0 += __shfl_xor(s0, 2); s0 += __shfl_xor(s0, 4);
        s0 += __shfl_xor(s0, 8); s0 += __shfl_xor(s0, 16);
        s1 += __shfl_xor(s1, 1); s1 += __shfl_xor(s1, 2); s1 += __shfl_xor(s1, 4);
        s1 += __shfl_xor(s1, 8); s1 += __shfl_xor(s1, 16);
        if (l32 == 0) {
            int rg = r0 + rr2;
            float v0 = s0 + ldin<BF>(ob, 0);
            float v1 = s1 + ldin<BF>(ob, 1);
            if (BF) {
                ((__hip_bfloat16*)out)[rg * 2 + 0] = __float2bfloat16(v0);
                ((__hip_bfloat16*)out)[rg * 2 + 1] = __float2bfloat16(v1);
            } else {
                ((float*)out)[rg * 2 + 0] = v0;
                ((float*)out)[rg * 2 + 1] = v1;
            }
        }
        return;
    }
    // ---- phase B: gs/gd for next layer from sh (half -> Wl/Wr) ----
    {
        const void* Wm = half ? Wr : Wl;
        const void* bm = half ? br : bl;
        float acc2[RB];
        float bn = ldin<BF>(bm, nbOff + d);
#pragma unroll
        for (int rr = 0; rr < RB; rr++) acc2[rr] = bn;
#pragma unroll
        for (int c = 0; c < 4; c++) {
            float w[32];
            ldw32<BF>(Wm, nwOff + d * DD + c * 32, w);
#pragma unroll
            for (int rr = 0; rr < RB; rr++) {
                const float* s = sh + rr * DD + c * 32;
                float a = acc2[rr];
#pragma unroll
                for (int k = 0; k < 32; k++) a += s[k] * w[k];
                acc2[rr] = a;
            }
        }
        if (half) {
#pragma unroll
            for (int rr = 0; rr < RB; rr++) gd[(size_t)(r0 + rr) * DD + d] = acc2[rr];
        } else {
#pragma unroll
            for (int rr = 0; rr < RB; rr++) {
                gs[(size_t)(r0 + rr) * DD + d] = acc2[rr];
                s_gs[rr * DD + d] = acc2[rr];
            }
        }
    }
    __syncthreads();
    // ---- gs_t4 write via LDS transpose: lane -> (d4 = t>>3, iL = t&7), i-contiguous ----
    {
        int d4 = t >> 3, iL = t & 7;
        int rg = r0 + iL;
        int bb2 = rg / NN, ii = rg - bb2 * NN;
        float4 v;
        v.x = s_gs[iL * DD + d4 * 4 + 0];
        v.y = s_gs[iL * DD + d4 * 4 + 1];
        v.z = s_gs[iL * DD + d4 * 4 + 2];
        v.w = s_gs[iL * DD + d4 * 4 + 3];
        ((float4*)(gs_t4 + (size_t)bb2 * GT4B))[d4 * 208 + ii] = v;
    }
}
__global__ void k_linG(const unsigned* bits, int hasPre, int epi, int hasNext,
                       const float* in,
                       const void* xin, const void* W1, const void* b1,
                       const void* g1, const void* bv1,
                       const void* W, int wOff,
                       const void* bias, const void* g, const void* bv, int dOff,
                       const void* Wl, const void* bl, const void* Wr, const void* br,
                       int nwOff, int nbOff,
                       float* h, float* gs, float* gd, float* gs_t4,
                       const void* oW, const void* ob, void* out) {
    __shared__ __align__(16) float smem[LING_SMEM];
    if (bits[0] == BFBITS)
        linG_body<true>(smem, hasPre, epi, hasNext, in, xin, W1, b1, g1, bv1,
                        W, wOff, bias, g, bv, dOff,
                        Wl, bl, Wr, br, nwOff, nbOff, h, gs, gd, gs_t4, oW, ob, out);
    else
        linG_body<false>(smem, hasPre, epi, hasNext, in, xin, W1, b1, g1, bv1,
                         W, wOff, bias, g, bv, dOff,
                         Wl, bl, Wr, br, nwOff, nbOff, h, gs, gd, gs_t4, oW, ob, out);
}

// ---------- fused attention (1 target per block, 256 thr, XCD-swizzled) ----------
// smem floats: s_ge 12*132 | s_pe 8*212 | s_inv 8 | s_part 128 | s_cat 207
#define ATTN_SMEM (12*132 + 8*212 + 8 + 128 + 207)
template<bool BF>
__device__ void attn_body(float* smem, int l, const float* __restrict__ gs,
                          const float* __restrict__ gd, const float* __restrict__ et,
                          const float* __restrict__ gs_t4, const int* __restrict__ cat,
                          const void* att, const void* cb, float* __restrict__ o) {
    float* s_ge   = smem;                  // 1584
    float* s_pe   = s_ge + 12 * 132;       // 1696
    float* s_inv  = s_pe + 8 * 212;        // 8
    float* s_part = s_inv + 8;             // 128
    int*   s_cat  = (int*)(s_part + 128);  // 207
    int p = blockIdx.x;
    int r = (p & 7) * (ROWS / 8) + (p >> 3);
    int t = threadIdx.x, d = t & 127, seg = t >> 7;
    int b = r / NN, j = r - b * NN;
    for (int idx = t; idx < NN; idx += 256) s_cat[idx] = cat[idx * NN + j];
    for (int idx = t; idx < 12 * DD; idx += 256) {
        int c = idx >> 7, k = idx & 127;
        s_ge[c * 132 + k] = et[l * 12 * DD + idx] + gd[(size_t)r * DD + k];
    }
    __syncthreads();
    const float* gsb = gs + (size_t)b * NN * DD;
    // phase 1: one source per thread; att read from GLOBAL (uniform -> scalar cache)
    if (t < NN) {
        const float4* gt = ((const float4*)(gs_t4 + (size_t)b * GT4B)) + t;
        const float4* ge = (const float4*)(s_ge + s_cat[t] * 132);
        float acc[8];
#pragma unroll
        for (int hh = 0; hh < 8; hh++) acc[hh] = 0.f;
#pragma unroll
        for (int q = 0; q < 32; q++) {
            float4 g4 = gt[q * 208];
            float4 e4 = ge[q];
            float4 a4 = ld4<BF>(att, l * 32 + q);
            float z0 = g4.x + e4.x, z1 = g4.y + e4.y, z2 = g4.z + e4.z, z3 = g4.w + e4.w;
            z0 = fmaxf(z0, SLOPE * z0); z1 = fmaxf(z1, SLOPE * z1);
            z2 = fmaxf(z2, SLOPE * z2); z3 = fmaxf(z3, SLOPE * z3);
            acc[q >> 2] += a4.x * z0 + a4.y * z1 + a4.z * z2 + a4.w * z3;
        }
#pragma unroll
        for (int hh = 0; hh < 8; hh++) s_pe[hh * 212 + t] = acc[hh];
    }
    __syncthreads();
    // phase 2: per-head softmax (threads 0..127)
    if (t < 128) {
        int hh = t >> 4, l16 = t & 15;
        float vals[13]; float mx = -1e30f;
#pragma unroll
        for (int k = 0; k < 13; k++) {
            int i = l16 + 16 * k;
            vals[k] = (i < NN) ? s_pe[hh * 212 + i] : -1e30f;
            mx = fmaxf(mx, vals[k]);
        }
        mx = fmaxf(mx, __shfl_xor(mx, 1)); mx = fmaxf(mx, __shfl_xor(mx, 2));
        mx = fmaxf(mx, __shfl_xor(mx, 4)); mx = fmaxf(mx, __shfl_xor(mx, 8));
        float sum = 0.f;
#pragma unroll
        for (int k = 0; k < 13; k++) {
            int i = l16 + 16 * k;
            float e = (i < NN) ? __expf(vals[k] - mx) : 0.f;
            if (i < 208) s_pe[hh * 212 + i] = e;
            sum += e;
        }
        sum += __shfl_xor(sum, 1); sum += __shfl_xor(sum, 2);
        sum += __shfl_xor(sum, 4); sum += __shfl_xor(sum, 8);
        if (l16 == 0) s_inv[hh] = 1.f / sum;
    }
    __syncthreads();
    // phase 3: o[d] = sum_i e[h(d)][i] * gs[b][i][d], i-range split across seg
    {
        int hh = d >> 4;
        const float* ep = s_pe + hh * 212;
        const float* gp = gsb + d;
        float a0 = 0.f, a1 = 0.f, a2 = 0.f, a3 = 0.f;
        int i = seg * 104;
        int iend = seg ? NN : 104;
        for (; i + 8 <= iend; i += 8) {
            float g0 = gp[(i+0)*DD], g1 = gp[(i+1)*DD], g2 = gp[(i+2)*DD], g3 = gp[(i+3)*DD];
            float g4 = gp[(i+4)*DD], g5 = gp[(i+5)*DD], g6 = gp[(i+6)*DD], g7 = gp[(i+7)*DD];
            a0 = fmaf(ep[i+0], g0, a0); a1 = fmaf(ep[i+1], g1, a1);
            a2 = fmaf(ep[i+2], g2, a2); a3 = fmaf(ep[i+3], g3, a3);
            a0 = fmaf(ep[i+4], g4, a0); a1 = fmaf(ep[i+5], g5, a1);
            a2 = fmaf(ep[i+6], g6, a2); a3 = fmaf(ep[i+7], g7, a3);
        }
        for (; i < iend; i++) a0 = fmaf(ep[i], gp[i * DD], a0);
        float part = a0 + a1 + a2 + a3;
        if (seg) s_part[d] = part;
        __syncthreads();
        if (!seg) o[(size_t)r * DD + d] = (part + s_part[d]) * s_inv[hh] + ldin<BF>(cb, l * DD + d);
    }
}
__global__ void __launch_bounds__(256, 4)
k_attn(const unsigned* bits, int l, const float* gs, const float* gd, const float* et,
       const float* gs_t4, const int* cat, const void* att, const void* cb,
       float* o) {
    __shared__ __align__(16) float smem[ATTN_SMEM];
    if (bits[0] == BFBITS) attn_body<true>(smem, l, gs, gd, et, gs_t4, cat, att, cb, o);
    else                   attn_body<false>(smem, l, gs, gd, et, gs_t4, cat, att, cb, o);
}

extern "C" void kernel_launch(void* const* d_in, const int* in_sizes, int n_in,
                              void* d_out, int out_size, void* d_ws, size_t ws_size,
                              hipStream_t stream) {
    const void* x     = d_in[0];
    const int*  cat   = (const int*)d_in[1];
    const void* emb   = d_in[2];
    const void* in1W  = d_in[3];
    const void* in1b  = d_in[4];
    const void* ln1g  = d_in[5];
    const void* ln1b  = d_in[6];
    const void* in2W  = d_in[7];
    const void* in2b  = d_in[8];
    const void* ln2g  = d_in[9];
    const void* ln2b  = d_in[10];
    const void* Wl    = d_in[11];
    const void* bl    = d_in[12];
    const void* Wr    = d_in[13];
    const void* br    = d_in[14];
    const void* We    = d_in[15];
    const void* att   = d_in[16];
    const void* cb    = d_in[17];
    const void* pW    = d_in[18];
    const void* pb    = d_in[19];
    const void* lng   = d_in[20];
    const void* lnb   = d_in[21];
    const void* oW    = d_in[22];
    const void* ob    = d_in[23];

    const unsigned* bits = (const unsigned*)ln1g;

    float* ws  = (float*)d_ws;
    float* h     = ws + 16;
    float* gs    = h    + ROWS * DD;
    float* gd    = gs   + ROWS * DD;
    float* o     = gd   + ROWS * DD;
    float* et    = o    + ROWS * DD;     // L*12*DD
    float* gs_t4 = et   + LL * 12 * DD;  // BB*GT4B

    k_et<<<LL * 12, DD, 0, stream>>>(bits, emb, We, et);
    // fused: mlp1 -> input-MLP linear2 + LN -> h, plus layer-0 gs/gd/gs_t4
    k_linG<<<LBLK, 256, 0, stream>>>(bits, 1, 0, 1, (const float*)nullptr,
                                     x, in1W, in1b, ln1g, ln1b,
                                     in2W, 0, in2b, ln2g, ln2b, 0,
                                     Wl, bl, Wr, br, 0, 0,
                                     h, gs, gd, gs_t4, oW, ob, d_out);
    for (int l = 0; l < LL; l++) {
        k_attn<<<ROWS, 256, 0, stream>>>(bits, l, gs, gd, et, gs_t4, cat, att, cb, o);
        k_linG<<<LBLK, 256, 0, stream>>>(bits, 0, 1, (l < LL - 1) ? 1 : 0, o,
                                         x, in1W, in1b, ln1g, ln1b,
                                         pW, l * DD * DD, pb, lng, lnb, l * DD,
                                         Wl, bl, Wr, br, (l + 1) * DD * DD, (l + 1) * DD,
                                         h, gs, gd, gs_t4, oW, ob, d_out);
    }
}

// Round 16
// 323.267 us; speedup vs baseline: 1.0354x; 1.0354x over previous
//
#include <hip/hip_runtime.h>
#include <hip/hip_bf16.h>

#define NN 207
#define DD 128
#define LL 4
#define BB 16
#define ROWS (BB*NN)   // 3312
#define RB 8
#define LBLK (ROWS/RB) // 414
#define EPSV 1e-5f
#define SLOPE 0.2f
#define GT4B (32*208*4) // floats per batch in packed-transposed gs
#define WTM  16384      // floats per transposed weight matrix

#define BFBITS 0x3F803F80u

// ---------- dtype-flexible load ----------
template<bool BF>
__device__ __forceinline__ float ldin(const void* p, int i) {
    if (BF) {
        unsigned short u = ((const unsigned short*)p)[i];
        return __uint_as_float(((unsigned)u) << 16);
    } else {
        return ((const float*)p)[i];
    }
}

// load float4 worth (4 elems) at float4-index q from a (possibly bf16) array
template<bool BF>
__device__ __forceinline__ float4 ld4(const void* p, int q4) {
    if (BF) {
        uint2 u = ((const uint2*)p)[q4];
        float4 r;
        r.x = __uint_as_float(u.x << 16);
        r.y = __uint_as_float(u.x & 0xFFFF0000u);
        r.z = __uint_as_float(u.y << 16);
        r.w = __uint_as_float(u.y & 0xFFFF0000u);
        return r;
    } else {
        return ((const float4*)p)[q4];
    }
}

// dot of one weight row with sh[0..127] (k_et only)
template<bool BF>
__device__ __forceinline__ float rowdot(const void* W, int rowbase, const float* sh) {
    float acc = 0.f;
    if (BF) {
        const uint4* p = (const uint4*)((const unsigned short*)W + rowbase);
#pragma unroll
        for (int q = 0; q < DD / 8; q++) {
            uint4 u = p[q];
            const float* s = sh + q * 8;
            acc += __uint_as_float(u.x << 16)        * s[0];
            acc += __uint_as_float(u.x & 0xFFFF0000u) * s[1];
            acc += __uint_as_float(u.y << 16)        * s[2];
            acc += __uint_as_float(u.y & 0xFFFF0000u) * s[3];
            acc += __uint_as_float(u.z << 16)        * s[4];
            acc += __uint_as_float(u.z & 0xFFFF0000u) * s[5];
            acc += __uint_as_float(u.w << 16)        * s[6];
            acc += __uint_as_float(u.w & 0xFFFF0000u) * s[7];
        }
    } else {
        const float4* p = (const float4*)((const float*)W + rowbase);
#pragma unroll
        for (int q = 0; q < DD / 4; q++) {
            float4 u = p[q];
            const float* s = sh + q * 4;
            acc += u.x * s[0]; acc += u.y * s[1]; acc += u.z * s[2]; acc += u.w * s[3];
        }
    }
    return acc;
}

// ---------- one-time weight transpose: wt[m][k][d] = W_m[d][k] (f32) ----------
// m: 0 = in2W; 1..4 = pW[l]; 5..8 = Wl[l]; 9..12 = Wr[l]
template<bool BF>
__device__ void wt_body(const void* in2W, const void* pW, const void* Wl, const void* Wr,
                        float* wt) {
    int m = blockIdx.x >> 7, k = blockIdx.x & 127, d = threadIdx.x;
    const void* src; int off;
    if (m == 0)      { src = in2W; off = 0; }
    else if (m <= 4) { src = pW;  off = (m - 1) * WTM; }
    else if (m <= 8) { src = Wl;  off = (m - 5) * WTM; }
    else             { src = Wr;  off = (m - 9) * WTM; }
    wt[m * WTM + k * DD + d] = ldin<BF>(src, off + d * DD + k);
}
__global__ void k_wt(const unsigned* bits, const void* in2W, const void* pW,
                     const void* Wl, const void* Wr, float* wt) {
    if (bits[0] == BFBITS) wt_body<true>(in2W, pW, Wl, Wr, wt);
    else                   wt_body<false>(in2W, pW, Wl, Wr, wt);
}

// ---------- edge tables: et[l][c12][d] ----------
template<bool BF>
__device__ void et_body(float* sh, const void* emb, const void* We, float* et) {
    int l = blockIdx.x / 12, c = blockIdx.x % 12, d = threadIdx.x;
    sh[d] = ldin<BF>(emb, c * DD + d);
    __syncthreads();
    et[(l * 12 + c) * DD + d] = rowdot<BF>(We, l * DD * DD + d * DD, sh);
}
__global__ void k_et(const unsigned* bits, const void* emb, const void* We, float* et) {
    __shared__ __align__(16) float smem[DD];
    if (bits[0] == BFBITS) et_body<true>(smem, emb, We, et);
    else                   et_body<false>(smem, emb, We, et);
}

// ---------- fused: [optional mlp1] -> linear + LN (+ReLU+res) -> h,
//            then next gs/gd/gs_t4 OR output head.  Weights from transposed wt. ----------
// smem: sh[RB*DD] | so[RB*132] | stats[16] | s_gs[RB*128] (s_x aliases s_gs)
#define LING_SMEM (RB*DD + RB*132 + 16 + RB*128)
template<bool BF>
__device__ void linG_body(float* smem, int hasPre, int epi, int hasNext,
                          const float* __restrict__ in,
                          const void* xin, const void* W1, const void* b1,
                          const void* g1, const void* bv1,
                          const float* __restrict__ wt, int mA,
                          const void* bias, const void* g, const void* bv, int dOff,
                          int mL, int mR, const void* bl, const void* br, int nbOff,
                          float* __restrict__ h, float* __restrict__ gs,
                          float* __restrict__ gd, float* __restrict__ gs_t4,
                          const void* oW, const void* ob, void* out) {
    float* sh    = smem;
    float* so    = sh + RB * DD;
    float* stats = so + RB * 132;
    float* s_gs  = stats + 16;
    float* s_x   = s_gs;
    int r0 = blockIdx.x * RB;
    int t = threadIdx.x, d = t & 127, half = t >> 7;
    int rr2 = t >> 5, l32 = t & 31;

    if (hasPre) {
        // ---- inline mlp1: Linear(6->128) + LN1 + ReLU -> sh ----
        if (t < RB * 6) s_x[t] = ldin<BF>(xin, r0 * 6 + t);
        __syncthreads();
        if (half == 0) {
            float w6[6];
#pragma unroll
            for (int k = 0; k < 6; k++) w6[k] = ldin<BF>(W1, d * 6 + k);
            float b0p = ldin<BF>(b1, d);
#pragma unroll
            for (int rr = 0; rr < RB; rr++) {
                float a = b0p;
#pragma unroll
                for (int k = 0; k < 6; k++) a += w6[k] * s_x[rr * 6 + k];
                so[rr * 132 + d] = a;
            }
        }
        __syncthreads();
        float s = 0.f, sq = 0.f;
#pragma unroll
        for (int k = 0; k < 4; k++) { float v = so[rr2 * 132 + l32 + 32 * k]; s += v; sq += v * v; }
        s += __shfl_xor(s, 1); s += __shfl_xor(s, 2); s += __shfl_xor(s, 4);
        s += __shfl_xor(s, 8); s += __shfl_xor(s, 16);
        sq += __shfl_xor(sq, 1); sq += __shfl_xor(sq, 2); sq += __shfl_xor(sq, 4);
        sq += __shfl_xor(sq, 8); sq += __shfl_xor(sq, 16);
        if (l32 == 0) {
            float mean = s * (1.f / DD);
            float var = sq * (1.f / DD) - mean * mean;
            stats[rr2 * 2] = mean; stats[rr2 * 2 + 1] = rsqrtf(var + EPSV);
        }
        __syncthreads();
        float gvp = ldin<BF>(g1, d), bbp = ldin<BF>(bv1, d);
#pragma unroll
        for (int rr = 0; rr < 4; rr++) {
            int row = half * 4 + rr;
            float v = (so[row * 132 + d] - stats[row * 2]) * stats[row * 2 + 1] * gvp + bbp;
            sh[row * DD + d] = fmaxf(v, 0.f);
        }
        __syncthreads();
    } else {
        ((float4*)sh)[t] = ((const float4*)(in + (size_t)r0 * DD))[t];
        __syncthreads();
    }

    // ---- phase A: projection linear via transposed weights (coalesced dword) ----
    const float* WT = wt + mA * WTM;
    float acc[4];
    float b0 = ldin<BF>(bias, dOff + d);
#pragma unroll
    for (int rr = 0; rr < 4; rr++) acc[rr] = b0;
    {
        const float* xr = sh + half * 4 * DD;
        for (int k4 = 0; k4 < 32; k4++) {
            float4 xa = *(const float4*)(xr + 0 * DD + k4 * 4);
            float4 xb = *(const float4*)(xr + 1 * DD + k4 * 4);
            float4 xc = *(const float4*)(xr + 2 * DD + k4 * 4);
            float4 xd = *(const float4*)(xr + 3 * DD + k4 * 4);
            float w0 = WT[(k4 * 4 + 0) * DD + d];
            float w1 = WT[(k4 * 4 + 1) * DD + d];
            float w2 = WT[(k4 * 4 + 2) * DD + d];
            float w3 = WT[(k4 * 4 + 3) * DD + d];
            acc[0] += w0 * xa.x + w1 * xa.y + w2 * xa.z + w3 * xa.w;
            acc[1] += w0 * xb.x + w1 * xb.y + w2 * xb.z + w3 * xb.w;
            acc[2] += w0 * xc.x + w1 * xc.y + w2 * xc.z + w3 * xc.w;
            acc[3] += w0 * xd.x + w1 * xd.y + w2 * xd.z + w3 * xd.w;
        }
    }
    __syncthreads();
#pragma unroll
    for (int rr = 0; rr < 4; rr++) so[(half * 4 + rr) * 132 + d] = acc[rr];
    __syncthreads();
    // ---- LN stats (8 rows x 32 lanes) ----
    {
        float s = 0.f, sq = 0.f;
#pragma unroll
        for (int k = 0; k < 4; k++) { float v = so[rr2 * 132 + l32 + 32 * k]; s += v; sq += v * v; }
        s += __shfl_xor(s, 1); s += __shfl_xor(s, 2); s += __shfl_xor(s, 4);
        s += __shfl_xor(s, 8); s += __shfl_xor(s, 16);
        sq += __shfl_xor(sq, 1); sq += __shfl_xor(sq, 2); sq += __shfl_xor(sq, 4);
        sq += __shfl_xor(sq, 8); sq += __shfl_xor(sq, 16);
        if (l32 == 0) {
            float mean = s * (1.f / DD);
            float var = sq * (1.f / DD) - mean * mean;
            stats[rr2 * 2] = mean; stats[rr2 * 2 + 1] = rsqrtf(var + EPSV);
        }
    }
    __syncthreads();
    // ---- epilogue: h_new -> global h AND into sh ----
    float gv = ldin<BF>(g, dOff + d), bb = ldin<BF>(bv, dOff + d);
#pragma unroll
    for (int rr = 0; rr < 4; rr++) {
        int row = half * 4 + rr;
        int rg = r0 + row;
        float v = (so[row * 132 + d] - stats[row * 2]) * stats[row * 2 + 1] * gv + bb;
        float hn;
        if (epi) hn = h[(size_t)rg * DD + d] + fmaxf(v, 0.f);
        else     hn = v;
        h[(size_t)rg * DD + d] = hn;
        sh[row * DD + d] = hn;
    }
    __syncthreads();
    if (!hasNext) {
        // ---- output head ----
        float s0 = 0.f, s1 = 0.f;
#pragma unroll
        for (int k = 0; k < 4; k++) {
            int dd = l32 + 32 * k;
            float hv = sh[rr2 * DD + dd];
            s0 += hv * ldin<BF>(oW, dd);
            s1 += hv * ldin<BF>(oW, DD + dd);
        }
        s0 += __shfl_xor(s0, 1); s0 += __shfl_xor(s0, 2); s0 += __shfl_xor(s0, 4);
        s0 += __shfl_xor(s0, 8); s0 += __shfl_xor(s0, 16);
        s1 += __shfl_xor(s1, 1); s1 += __shfl_xor(s1, 2); s1 += __shfl_xor(s1, 4);
        s1 += __shfl_xor(s1, 8); s1 += __shfl_xor(s1, 16);
        if (l32 == 0) {
            int rg = r0 + rr2;
            float v0 = s0 + ldin<BF>(ob, 0);
            float v1 = s1 + ldin<BF>(ob, 1);
            if (BF) {
                ((__hip_bfloat16*)out)[rg * 2 + 0] = __float2bfloat16(v0);
                ((__hip_bfloat16*)out)[rg * 2 + 1] = __float2bfloat16(v1);
            } else {
                ((float*)out)[rg * 2 + 0] = v0;
                ((float*)out)[rg * 2 + 1] = v1;
            }
        }
        return;
    }
    // ---- phase B: gs/gd for next layer via transposed weights (half -> mL/mR) ----
    {
        const float* WTm = wt + (half ? mR : mL) * WTM;
        const void* bm = half ? br : bl;
        float acc2[RB];
        float bn = ldin<BF>(bm, nbOff + d);
#pragma unroll
        for (int rr = 0; rr < RB; rr++) acc2[rr] = bn;
        for (int k4 = 0; k4 < 32; k4++) {
            float4 x0 = *(const float4*)(sh + 0 * DD + k4 * 4);
            float4 x1 = *(const float4*)(sh + 1 * DD + k4 * 4);
            float4 x2 = *(const float4*)(sh + 2 * DD + k4 * 4);
            float4 x3 = *(const float4*)(sh + 3 * DD + k4 * 4);
            float4 x4 = *(const float4*)(sh + 4 * DD + k4 * 4);
            float4 x5 = *(const float4*)(sh + 5 * DD + k4 * 4);
            float4 x6 = *(const float4*)(sh + 6 * DD + k4 * 4);
            float4 x7 = *(const float4*)(sh + 7 * DD + k4 * 4);
            float w0 = WTm[(k4 * 4 + 0) * DD + d];
            float w1 = WTm[(k4 * 4 + 1) * DD + d];
            float w2 = WTm[(k4 * 4 + 2) * DD + d];
            float w3 = WTm[(k4 * 4 + 3) * DD + d];
            acc2[0] += w0 * x0.x + w1 * x0.y + w2 * x0.z + w3 * x0.w;
            acc2[1] += w0 * x1.x + w1 * x1.y + w2 * x1.z + w3 * x1.w;
            acc2[2] += w0 * x2.x + w1 * x2.y + w2 * x2.z + w3 * x2.w;
            acc2[3] += w0 * x3.x + w1 * x3.y + w2 * x3.z + w3 * x3.w;
            acc2[4] += w0 * x4.x + w1 * x4.y + w2 * x4.z + w3 * x4.w;
            acc2[5] += w0 * x5.x + w1 * x5.y + w2 * x5.z + w3 * x5.w;
            acc2[6] += w0 * x6.x + w1 * x6.y + w2 * x6.z + w3 * x6.w;
            acc2[7] += w0 * x7.x + w1 * x7.y + w2 * x7.z + w3 * x7.w;
        }
        if (half) {
#pragma unroll
            for (int rr = 0; rr < RB; rr++) gd[(size_t)(r0 + rr) * DD + d] = acc2[rr];
        } else {
#pragma unroll
            for (int rr = 0; rr < RB; rr++) {
                gs[(size_t)(r0 + rr) * DD + d] = acc2[rr];
                s_gs[rr * DD + d] = acc2[rr];
            }
        }
    }
    __syncthreads();
    // ---- gs_t4 write via LDS transpose: lane -> (d4 = t>>3, iL = t&7), i-contiguous ----
    {
        int d4 = t >> 3, iL = t & 7;
        int rg = r0 + iL;
        int bb2 = rg / NN, ii = rg - bb2 * NN;
        float4 v;
        v.x = s_gs[iL * DD + d4 * 4 + 0];
        v.y = s_gs[iL * DD + d4 * 4 + 1];
        v.z = s_gs[iL * DD + d4 * 4 + 2];
        v.w = s_gs[iL * DD + d4 * 4 + 3];
        ((float4*)(gs_t4 + (size_t)bb2 * GT4B))[d4 * 208 + ii] = v;
    }
}
__global__ void k_linG(const unsigned* bits, int hasPre, int epi, int hasNext,
                       const float* in,
                       const void* xin, const void* W1, const void* b1,
                       const void* g1, const void* bv1,
                       const float* wt, int mA,
                       const void* bias, const void* g, const void* bv, int dOff,
                       int mL, int mR, const void* bl, const void* br, int nbOff,
                       float* h, float* gs, float* gd, float* gs_t4,
                       const void* oW, const void* ob, void* out) {
    __shared__ __align__(16) float smem[LING_SMEM];
    if (bits[0] == BFBITS)
        linG_body<true>(smem, hasPre, epi, hasNext, in, xin, W1, b1, g1, bv1,
                        wt, mA, bias, g, bv, dOff, mL, mR, bl, br, nbOff,
                        h, gs, gd, gs_t4, oW, ob, out);
    else
        linG_body<false>(smem, hasPre, epi, hasNext, in, xin, W1, b1, g1, bv1,
                         wt, mA, bias, g, bv, dOff, mL, mR, bl, br, nbOff,
                         h, gs, gd, gs_t4, oW, ob, out);
}

// ---------- fused attention (1 target per block, 256 thr, XCD-swizzled) ----------
// smem floats: s_ge 12*132 | s_pe 8*212 | s_inv 8 | s_part 128 | s_cat 207
#define ATTN_SMEM (12*132 + 8*212 + 8 + 128 + 207)
template<bool BF>
__device__ void attn_body(float* smem, int l, const float* __restrict__ gs,
                          const float* __restrict__ gd, const float* __restrict__ et,
                          const float* __restrict__ gs_t4, const int* __restrict__ cat,
                          const void* att, const void* cb, float* __restrict__ o) {
    float* s_ge   = smem;                  // 1584
    float* s_pe   = s_ge + 12 * 132;       // 1696
    float* s_inv  = s_pe + 8 * 212;        // 8
    float* s_part = s_inv + 8;             // 128
    int*   s_cat  = (int*)(s_part + 128);  // 207
    int p = blockIdx.x;
    int r = (p & 7) * (ROWS / 8) + (p >> 3);
    int t = threadIdx.x, d = t & 127, seg = t >> 7;
    int b = r / NN, j = r - b * NN;
    for (int idx = t; idx < NN; idx += 256) s_cat[idx] = cat[idx * NN + j];
    for (int idx = t; idx < 12 * DD; idx += 256) {
        int c = idx >> 7, k = idx & 127;
        s_ge[c * 132 + k] = et[l * 12 * DD + idx] + gd[(size_t)r * DD + k];
    }
    __syncthreads();
    const float* gsb = gs + (size_t)b * NN * DD;
    // phase 1: one source per thread; att read from GLOBAL (uniform -> scalar cache)
    if (t < NN) {
        const float4* gt = ((const float4*)(gs_t4 + (size_t)b * GT4B)) + t;
        const float4* ge = (const float4*)(s_ge + s_cat[t] * 132);
        float acc[8];
#pragma unroll
        for (int hh = 0; hh < 8; hh++) acc[hh] = 0.f;
#pragma unroll
        for (int q = 0; q < 32; q++) {
            float4 g4 = gt[q * 208];
            float4 e4 = ge[q];
            float4 a4 = ld4<BF>(att, l * 32 + q);
            float z0 = g4.x + e4.x, z1 = g4.y + e4.y, z2 = g4.z + e4.z, z3 = g4.w + e4.w;
            z0 = fmaxf(z0, SLOPE * z0); z1 = fmaxf(z1, SLOPE * z1);
            z2 = fmaxf(z2, SLOPE * z2); z3 = fmaxf(z3, SLOPE * z3);
            acc[q >> 2] += a4.x * z0 + a4.y * z1 + a4.z * z2 + a4.w * z3;
        }
#pragma unroll
        for (int hh = 0; hh < 8; hh++) s_pe[hh * 212 + t] = acc[hh];
    }
    __syncthreads();
    // phase 2: per-head softmax (threads 0..127)
    if (t < 128) {
        int hh = t >> 4, l16 = t & 15;
        float vals[13]; float mx = -1e30f;
#pragma unroll
        for (int k = 0; k < 13; k++) {
            int i = l16 + 16 * k;
            vals[k] = (i < NN) ? s_pe[hh * 212 + i] : -1e30f;
            mx = fmaxf(mx, vals[k]);
        }
        mx = fmaxf(mx, __shfl_xor(mx, 1)); mx = fmaxf(mx, __shfl_xor(mx, 2));
        mx = fmaxf(mx, __shfl_xor(mx, 4)); mx = fmaxf(mx, __shfl_xor(mx, 8));
        float sum = 0.f;
#pragma unroll
        for (int k = 0; k < 13; k++) {
            int i = l16 + 16 * k;
            float e = (i < NN) ? __expf(vals[k] - mx) : 0.f;
            if (i < 208) s_pe[hh * 212 + i] = e;
            sum += e;
        }
        sum += __shfl_xor(sum, 1); sum += __shfl_xor(sum, 2);
        sum += __shfl_xor(sum, 4); sum += __shfl_xor(sum, 8);
        if (l16 == 0) s_inv[hh] = 1.f / sum;
    }
    __syncthreads();
    // phase 3: o[d] = sum_i e[h(d)][i] * gs[b][i][d], i-range split across seg
    {
        int hh = d >> 4;
        const float* ep = s_pe + hh * 212;
        const float* gp = gsb + d;
        float a0 = 0.f, a1 = 0.f, a2 = 0.f, a3 = 0.f;
        int i = seg * 104;
        int iend = seg ? NN : 104;
        for (; i + 8 <= iend; i += 8) {
            float g0 = gp[(i+0)*DD], g1 = gp[(i+1)*DD], g2 = gp[(i+2)*DD], g3 = gp[(i+3)*DD];
            float g4 = gp[(i+4)*DD], g5 = gp[(i+5)*DD], g6 = gp[(i+6)*DD], g7 = gp[(i+7)*DD];
            a0 = fmaf(ep[i+0], g0, a0); a1 = fmaf(ep[i+1], g1, a1);
            a2 = fmaf(ep[i+2], g2, a2); a3 = fmaf(ep[i+3], g3, a3);
            a0 = fmaf(ep[i+4], g4, a0); a1 = fmaf(ep[i+5], g5, a1);
            a2 = fmaf(ep[i+6], g6, a2); a3 = fmaf(ep[i+7], g7, a3);
        }
        for (; i < iend; i++) a0 = fmaf(ep[i], gp[i * DD], a0);
        float part = a0 + a1 + a2 + a3;
        if (seg) s_part[d] = part;
        __syncthreads();
        if (!seg) o[(size_t)r * DD + d] = (part + s_part[d]) * s_inv[hh] + ldin<BF>(cb, l * DD + d);
    }
}
__global__ void __launch_bounds__(256, 4)
k_attn(const unsigned* bits, int l, const float* gs, const float* gd, const float* et,
       const float* gs_t4, const int* cat, const void* att, const void* cb,
       float* o) {
    __shared__ __align__(16) float smem[ATTN_SMEM];
    if (bits[0] == BFBITS) attn_body<true>(smem, l, gs, gd, et, gs_t4, cat, att, cb, o);
    else                   attn_body<false>(smem, l, gs, gd, et, gs_t4, cat, att, cb, o);
}

extern "C" void kernel_launch(void* const* d_in, const int* in_sizes, int n_in,
                              void* d_out, int out_size, void* d_ws, size_t ws_size,
                              hipStream_t stream) {
    const void* x     = d_in[0];
    const int*  cat   = (const int*)d_in[1];
    const void* emb   = d_in[2];
    const void* in1W  = d_in[3];
    const void* in1b  = d_in[4];
    const void* ln1g  = d_in[5];
    const void* ln1b  = d_in[6];
    const void* in2W  = d_in[7];
    const void* in2b  = d_in[8];
    const void* ln2g  = d_in[9];
    const void* ln2b  = d_in[10];
    const void* Wl    = d_in[11];
    const void* bl    = d_in[12];
    const void* Wr    = d_in[13];
    const void* br    = d_in[14];
    const void* We    = d_in[15];
    const void* att   = d_in[16];
    const void* cb    = d_in[17];
    const void* pW    = d_in[18];
    const void* pb    = d_in[19];
    const void* lng   = d_in[20];
    const void* lnb   = d_in[21];
    const void* oW    = d_in[22];
    const void* ob    = d_in[23];

    const unsigned* bits = (const unsigned*)ln1g;

    float* ws  = (float*)d_ws;
    float* h     = ws + 16;
    float* gs    = h    + ROWS * DD;
    float* gd    = gs   + ROWS * DD;
    float* o     = gd   + ROWS * DD;
    float* et    = o    + ROWS * DD;     // L*12*DD
    float* gs_t4 = et   + LL * 12 * DD;  // BB*GT4B
    float* wt    = gs_t4 + (size_t)BB * GT4B;  // 13*WTM

    k_wt<<<13 * 128, 128, 0, stream>>>(bits, in2W, pW, Wl, Wr, wt);
    k_et<<<LL * 12, DD, 0, stream>>>(bits, emb, We, et);
    // fused: mlp1 -> input-MLP linear2 + LN -> h, plus layer-0 gs/gd/gs_t4
    k_linG<<<LBLK, 256, 0, stream>>>(bits, 1, 0, 1, (const float*)nullptr,
                                     x, in1W, in1b, ln1g, ln1b,
                                     wt, 0, in2b, ln2g, ln2b, 0,
                                     5, 9, bl, br, 0,
                                     h, gs, gd, gs_t4, oW, ob, d_out);
    for (int l = 0; l < LL; l++) {
        k_attn<<<ROWS, 256, 0, stream>>>(bits, l, gs, gd, et, gs_t4, cat, att, cb, o);
        k_linG<<<LBLK, 256, 0, stream>>>(bits, 0, 1, (l < LL - 1) ? 1 : 0, o,
                                         x, in1W, in1b, ln1g, ln1b,
                                         wt, 1 + l, pb, lng, lnb, l * DD,
                                         5 + (l + 1), 9 + (l + 1), bl, br, (l + 1) * DD,
                                         h, gs, gd, gs_t4, oW, ob, d_out);
    }
}

// Round 17
// 320.008 us; speedup vs baseline: 1.0460x; 1.0102x over previous
//
#include <hip/hip_runtime.h>
#include <hip/hip_bf16.h>

#define NN 207
#define DD 128
#define LL 4
#define BB 16
#define ROWS (BB*NN)   // 3312
#define RB 8
#define LBLK (ROWS/RB) // 414
#define EPSV 1e-5f
#define SLOPE 0.2f
#define GT4B (32*208*4) // floats per batch in packed-transposed gs
#define WTM  16384      // floats per transposed weight matrix

#define BFBITS 0x3F803F80u

// ---------- dtype-flexible load ----------
template<bool BF>
__device__ __forceinline__ float ldin(const void* p, int i) {
    if (BF) {
        unsigned short u = ((const unsigned short*)p)[i];
        return __uint_as_float(((unsigned)u) << 16);
    } else {
        return ((const float*)p)[i];
    }
}

// load float4 worth (4 elems) at float4-index q from a (possibly bf16) array
template<bool BF>
__device__ __forceinline__ float4 ld4(const void* p, int q4) {
    if (BF) {
        uint2 u = ((const uint2*)p)[q4];
        float4 r;
        r.x = __uint_as_float(u.x << 16);
        r.y = __uint_as_float(u.x & 0xFFFF0000u);
        r.z = __uint_as_float(u.y << 16);
        r.w = __uint_as_float(u.y & 0xFFFF0000u);
        return r;
    } else {
        return ((const float4*)p)[q4];
    }
}

// dot of one weight row with sh[0..127] (k_et only)
template<bool BF>
__device__ __forceinline__ float rowdot(const void* W, int rowbase, const float* sh) {
    float acc = 0.f;
    if (BF) {
        const uint4* p = (const uint4*)((const unsigned short*)W + rowbase);
#pragma unroll
        for (int q = 0; q < DD / 8; q++) {
            uint4 u = p[q];
            const float* s = sh + q * 8;
            acc += __uint_as_float(u.x << 16)        * s[0];
            acc += __uint_as_float(u.x & 0xFFFF0000u) * s[1];
            acc += __uint_as_float(u.y << 16)        * s[2];
            acc += __uint_as_float(u.y & 0xFFFF0000u) * s[3];
            acc += __uint_as_float(u.z << 16)        * s[4];
            acc += __uint_as_float(u.z & 0xFFFF0000u) * s[5];
            acc += __uint_as_float(u.w << 16)        * s[6];
            acc += __uint_as_float(u.w & 0xFFFF0000u) * s[7];
        }
    } else {
        const float4* p = (const float4*)((const float*)W + rowbase);
#pragma unroll
        for (int q = 0; q < DD / 4; q++) {
            float4 u = p[q];
            const float* s = sh + q * 4;
            acc += u.x * s[0]; acc += u.y * s[1]; acc += u.z * s[2]; acc += u.w * s[3];
        }
    }
    return acc;
}

// ---------- one-time weight transpose: wt[m][k][d] = W_m[d][k] (f32) ----------
// m: 0 = in2W; 1..4 = pW[l]; 5..8 = Wl[l]; 9..12 = Wr[l]
template<bool BF>
__device__ void wt_body(const void* in2W, const void* pW, const void* Wl, const void* Wr,
                        float* wt) {
    int m = blockIdx.x >> 7, k = blockIdx.x & 127, d = threadIdx.x;
    const void* src; int off;
    if (m == 0)      { src = in2W; off = 0; }
    else if (m <= 4) { src = pW;  off = (m - 1) * WTM; }
    else if (m <= 8) { src = Wl;  off = (m - 5) * WTM; }
    else             { src = Wr;  off = (m - 9) * WTM; }
    wt[m * WTM + k * DD + d] = ldin<BF>(src, off + d * DD + k);
}
__global__ void k_wt(const unsigned* bits, const void* in2W, const void* pW,
                     const void* Wl, const void* Wr, float* wt) {
    if (bits[0] == BFBITS) wt_body<true>(in2W, pW, Wl, Wr, wt);
    else                   wt_body<false>(in2W, pW, Wl, Wr, wt);
}

// ---------- edge tables: et[l][c12][d] ----------
template<bool BF>
__device__ void et_body(float* sh, const void* emb, const void* We, float* et) {
    int l = blockIdx.x / 12, c = blockIdx.x % 12, d = threadIdx.x;
    sh[d] = ldin<BF>(emb, c * DD + d);
    __syncthreads();
    et[(l * 12 + c) * DD + d] = rowdot<BF>(We, l * DD * DD + d * DD, sh);
}
__global__ void k_et(const unsigned* bits, const void* emb, const void* We, float* et) {
    __shared__ __align__(16) float smem[DD];
    if (bits[0] == BFBITS) et_body<true>(smem, emb, We, et);
    else                   et_body<false>(smem, emb, We, et);
}

// ---------- fused: [optional mlp1] -> linear + LN (+ReLU+res) -> h,
//            then next gs/gd/gs_t4 OR output head.  Weights from transposed wt. ----------
// smem: sh[RB*DD] | so[RB*132] | stats[16] | s_gs[RB*128] (s_x aliases s_gs)
#define LING_SMEM (RB*DD + RB*132 + 16 + RB*128)
template<bool BF>
__device__ void linG_body(float* smem, int hasPre, int epi, int hasNext,
                          const float* __restrict__ in,
                          const void* xin, const void* W1, const void* b1,
                          const void* g1, const void* bv1,
                          const float* __restrict__ wt, int mA,
                          const void* bias, const void* g, const void* bv, int dOff,
                          int mL, int mR, const void* bl, const void* br, int nbOff,
                          float* __restrict__ h, float* __restrict__ gs,
                          float* __restrict__ gd, float* __restrict__ gs_t4,
                          const void* oW, const void* ob, void* out) {
    float* sh    = smem;
    float* so    = sh + RB * DD;
    float* stats = so + RB * 132;
    float* s_gs  = stats + 16;
    float* s_x   = s_gs;
    int r0 = blockIdx.x * RB;
    int t = threadIdx.x, d = t & 127, half = t >> 7;
    int rr2 = t >> 5, l32 = t & 31;

    if (hasPre) {
        // ---- inline mlp1: Linear(6->128) + LN1 + ReLU -> sh ----
        if (t < RB * 6) s_x[t] = ldin<BF>(xin, r0 * 6 + t);
        __syncthreads();
        if (half == 0) {
            float w6[6];
#pragma unroll
            for (int k = 0; k < 6; k++) w6[k] = ldin<BF>(W1, d * 6 + k);
            float b0p = ldin<BF>(b1, d);
#pragma unroll
            for (int rr = 0; rr < RB; rr++) {
                float a = b0p;
#pragma unroll
                for (int k = 0; k < 6; k++) a += w6[k] * s_x[rr * 6 + k];
                so[rr * 132 + d] = a;
            }
        }
        __syncthreads();
        float s = 0.f, sq = 0.f;
#pragma unroll
        for (int k = 0; k < 4; k++) { float v = so[rr2 * 132 + l32 + 32 * k]; s += v; sq += v * v; }
        s += __shfl_xor(s, 1); s += __shfl_xor(s, 2); s += __shfl_xor(s, 4);
        s += __shfl_xor(s, 8); s += __shfl_xor(s, 16);
        sq += __shfl_xor(sq, 1); sq += __shfl_xor(sq, 2); sq += __shfl_xor(sq, 4);
        sq += __shfl_xor(sq, 8); sq += __shfl_xor(sq, 16);
        if (l32 == 0) {
            float mean = s * (1.f / DD);
            float var = sq * (1.f / DD) - mean * mean;
            stats[rr2 * 2] = mean; stats[rr2 * 2 + 1] = rsqrtf(var + EPSV);
        }
        __syncthreads();
        float gvp = ldin<BF>(g1, d), bbp = ldin<BF>(bv1, d);
#pragma unroll
        for (int rr = 0; rr < 4; rr++) {
            int row = half * 4 + rr;
            float v = (so[row * 132 + d] - stats[row * 2]) * stats[row * 2 + 1] * gvp + bbp;
            sh[row * DD + d] = fmaxf(v, 0.f);
        }
        __syncthreads();
    } else {
        ((float4*)sh)[t] = ((const float4*)(in + (size_t)r0 * DD))[t];
        __syncthreads();
    }

    // ---- phase A: projection linear via transposed weights (coalesced dword) ----
    const float* WT = wt + mA * WTM;
    float acc[4];
    float b0 = ldin<BF>(bias, dOff + d);
#pragma unroll
    for (int rr = 0; rr < 4; rr++) acc[rr] = b0;
    {
        const float* xr = sh + half * 4 * DD;
        for (int k4 = 0; k4 < 32; k4++) {
            float4 xa = *(const float4*)(xr + 0 * DD + k4 * 4);
            float4 xb = *(const float4*)(xr + 1 * DD + k4 * 4);
            float4 xc = *(const float4*)(xr + 2 * DD + k4 * 4);
            float4 xd = *(const float4*)(xr + 3 * DD + k4 * 4);
            float w0 = WT[(k4 * 4 + 0) * DD + d];
            float w1 = WT[(k4 * 4 + 1) * DD + d];
            float w2 = WT[(k4 * 4 + 2) * DD + d];
            float w3 = WT[(k4 * 4 + 3) * DD + d];
            acc[0] += w0 * xa.x + w1 * xa.y + w2 * xa.z + w3 * xa.w;
            acc[1] += w0 * xb.x + w1 * xb.y + w2 * xb.z + w3 * xb.w;
            acc[2] += w0 * xc.x + w1 * xc.y + w2 * xc.z + w3 * xc.w;
            acc[3] += w0 * xd.x + w1 * xd.y + w2 * xd.z + w3 * xd.w;
        }
    }
    __syncthreads();
#pragma unroll
    for (int rr = 0; rr < 4; rr++) so[(half * 4 + rr) * 132 + d] = acc[rr];
    __syncthreads();
    // ---- LN stats (8 rows x 32 lanes) ----
    {
        float s = 0.f, sq = 0.f;
#pragma unroll
        for (int k = 0; k < 4; k++) { float v = so[rr2 * 132 + l32 + 32 * k]; s += v; sq += v * v; }
        s += __shfl_xor(s, 1); s += __shfl_xor(s, 2); s += __shfl_xor(s, 4);
        s += __shfl_xor(s, 8); s += __shfl_xor(s, 16);
        sq += __shfl_xor(sq, 1); sq += __shfl_xor(sq, 2); sq += __shfl_xor(sq, 4);
        sq += __shfl_xor(sq, 8); sq += __shfl_xor(sq, 16);
        if (l32 == 0) {
            float mean = s * (1.f / DD);
            float var = sq * (1.f / DD) - mean * mean;
            stats[rr2 * 2] = mean; stats[rr2 * 2 + 1] = rsqrtf(var + EPSV);
        }
    }
    __syncthreads();
    // ---- epilogue: h_new -> global h AND into sh ----
    float gv = ldin<BF>(g, dOff + d), bb = ldin<BF>(bv, dOff + d);
#pragma unroll
    for (int rr = 0; rr < 4; rr++) {
        int row = half * 4 + rr;
        int rg = r0 + row;
        float v = (so[row * 132 + d] - stats[row * 2]) * stats[row * 2 + 1] * gv + bb;
        float hn;
        if (epi) hn = h[(size_t)rg * DD + d] + fmaxf(v, 0.f);
        else     hn = v;
        h[(size_t)rg * DD + d] = hn;
        sh[row * DD + d] = hn;
    }
    __syncthreads();
    if (!hasNext) {
        // ---- output head ----
        float s0 = 0.f, s1 = 0.f;
#pragma unroll
        for (int k = 0; k < 4; k++) {
            int dd = l32 + 32 * k;
            float hv = sh[rr2 * DD + dd];
            s0 += hv * ldin<BF>(oW, dd);
            s1 += hv * ldin<BF>(oW, DD + dd);
        }
        s0 += __shfl_xor(s0, 1); s0 += __shfl_xor(s0, 2); s0 += __shfl_xor(s0, 4);
        s0 += __shfl_xor(s0, 8); s0 += __shfl_xor(s0, 16);
        s1 += __shfl_xor(s1, 1); s1 += __shfl_xor(s1, 2); s1 += __shfl_xor(s1, 4);
        s1 += __shfl_xor(s1, 8); s1 += __shfl_xor(s1, 16);
        if (l32 == 0) {
            int rg = r0 + rr2;
            float v0 = s0 + ldin<BF>(ob, 0);
            float v1 = s1 + ldin<BF>(ob, 1);
            if (BF) {
                ((__hip_bfloat16*)out)[rg * 2 + 0] = __float2bfloat16(v0);
                ((__hip_bfloat16*)out)[rg * 2 + 1] = __float2bfloat16(v1);
            } else {
                ((float*)out)[rg * 2 + 0] = v0;
                ((float*)out)[rg * 2 + 1] = v1;
            }
        }
        return;
    }
    // ---- phase B: gs/gd for next layer via transposed weights (half -> mL/mR) ----
    {
        const float* WTm = wt + (half ? mR : mL) * WTM;
        const void* bm = half ? br : bl;
        float acc2[RB];
        float bn = ldin<BF>(bm, nbOff + d);
#pragma unroll
        for (int rr = 0; rr < RB; rr++) acc2[rr] = bn;
        for (int k4 = 0; k4 < 32; k4++) {
            float4 x0 = *(const float4*)(sh + 0 * DD + k4 * 4);
            float4 x1 = *(const float4*)(sh + 1 * DD + k4 * 4);
            float4 x2 = *(const float4*)(sh + 2 * DD + k4 * 4);
            float4 x3 = *(const float4*)(sh + 3 * DD + k4 * 4);
            float4 x4 = *(const float4*)(sh + 4 * DD + k4 * 4);
            float4 x5 = *(const float4*)(sh + 5 * DD + k4 * 4);
            float4 x6 = *(const float4*)(sh + 6 * DD + k4 * 4);
            float4 x7 = *(const float4*)(sh + 7 * DD + k4 * 4);
            float w0 = WTm[(k4 * 4 + 0) * DD + d];
            float w1 = WTm[(k4 * 4 + 1) * DD + d];
            float w2 = WTm[(k4 * 4 + 2) * DD + d];
            float w3 = WTm[(k4 * 4 + 3) * DD + d];
            acc2[0] += w0 * x0.x + w1 * x0.y + w2 * x0.z + w3 * x0.w;
            acc2[1] += w0 * x1.x + w1 * x1.y + w2 * x1.z + w3 * x1.w;
            acc2[2] += w0 * x2.x + w1 * x2.y + w2 * x2.z + w3 * x2.w;
            acc2[3] += w0 * x3.x + w1 * x3.y + w2 * x3.z + w3 * x3.w;
            acc2[4] += w0 * x4.x + w1 * x4.y + w2 * x4.z + w3 * x4.w;
            acc2[5] += w0 * x5.x + w1 * x5.y + w2 * x5.z + w3 * x5.w;
            acc2[6] += w0 * x6.x + w1 * x6.y + w2 * x6.z + w3 * x6.w;
            acc2[7] += w0 * x7.x + w1 * x7.y + w2 * x7.z + w3 * x7.w;
        }
        if (half) {
#pragma unroll
            for (int rr = 0; rr < RB; rr++) gd[(size_t)(r0 + rr) * DD + d] = acc2[rr];
        } else {
#pragma unroll
            for (int rr = 0; rr < RB; rr++) {
                gs[(size_t)(r0 + rr) * DD + d] = acc2[rr];
                s_gs[rr * DD + d] = acc2[rr];
            }
        }
    }
    __syncthreads();
    // ---- gs_t4 write via LDS transpose: lane -> (d4 = t>>3, iL = t&7), i-contiguous ----
    {
        int d4 = t >> 3, iL = t & 7;
        int rg = r0 + iL;
        int bb2 = rg / NN, ii = rg - bb2 * NN;
        float4 v;
        v.x = s_gs[iL * DD + d4 * 4 + 0];
        v.y = s_gs[iL * DD + d4 * 4 + 1];
        v.z = s_gs[iL * DD + d4 * 4 + 2];
        v.w = s_gs[iL * DD + d4 * 4 + 3];
        ((float4*)(gs_t4 + (size_t)bb2 * GT4B))[d4 * 208 + ii] = v;
    }
}
__global__ void k_linG(const unsigned* bits, int hasPre, int epi, int hasNext,
                       const float* in,
                       const void* xin, const void* W1, const void* b1,
                       const void* g1, const void* bv1,
                       const float* wt, int mA,
                       const void* bias, const void* g, const void* bv, int dOff,
                       int mL, int mR, const void* bl, const void* br, int nbOff,
                       float* h, float* gs, float* gd, float* gs_t4,
                       const void* oW, const void* ob, void* out) {
    __shared__ __align__(16) float smem[LING_SMEM];
    if (bits[0] == BFBITS)
        linG_body<true>(smem, hasPre, epi, hasNext, in, xin, W1, b1, g1, bv1,
                        wt, mA, bias, g, bv, dOff, mL, mR, bl, br, nbOff,
                        h, gs, gd, gs_t4, oW, ob, out);
    else
        linG_body<false>(smem, hasPre, epi, hasNext, in, xin, W1, b1, g1, bv1,
                         wt, mA, bias, g, bv, dOff, mL, mR, bl, br, nbOff,
                         h, gs, gd, gs_t4, oW, ob, out);
}

// ---------- fused attention (1 target per block, 256 thr, XCD-swizzled) ----------
// smem floats: s_ge 12*132 | s_pe 8*212 | s_inv 8 | s_part 128 | s_cat 207
#define ATTN_SMEM (12*132 + 8*212 + 8 + 128 + 207)
template<bool BF>
__device__ void attn_body(float* smem, int l, const float* __restrict__ gs,
                          const float* __restrict__ gd, const float* __restrict__ et,
                          const float* __restrict__ gs_t4, const int* __restrict__ cat,
                          const void* att, const void* cb, float* __restrict__ o) {
    float* s_ge   = smem;                  // 1584
    float* s_pe   = s_ge + 12 * 132;       // 1696
    float* s_inv  = s_pe + 8 * 212;        // 8
    float* s_part = s_inv + 8;             // 128
    int*   s_cat  = (int*)(s_part + 128);  // 207
    int p = blockIdx.x;
    int r = (p & 7) * (ROWS / 8) + (p >> 3);
    int t = threadIdx.x, d = t & 127, seg = t >> 7;
    int b = r / NN, j = r - b * NN;
    for (int idx = t; idx < NN; idx += 256) s_cat[idx] = cat[idx * NN + j];
    for (int idx = t; idx < 12 * DD; idx += 256) {
        int c = idx >> 7, k = idx & 127;
        s_ge[c * 132 + k] = et[l * 12 * DD + idx] + gd[(size_t)r * DD + k];
    }
    __syncthreads();
    const float* gsb = gs + (size_t)b * NN * DD;
    // phase 1: one source per thread; att read from GLOBAL (uniform -> scalar cache)
    if (t < NN) {
        const float4* gt = ((const float4*)(gs_t4 + (size_t)b * GT4B)) + t;
        const float4* ge = (const float4*)(s_ge + s_cat[t] * 132);
        float acc[8];
#pragma unroll
        for (int hh = 0; hh < 8; hh++) acc[hh] = 0.f;
#pragma unroll
        for (int q = 0; q < 32; q++) {
            float4 g4 = gt[q * 208];
            float4 e4 = ge[q];
            float4 a4 = ld4<BF>(att, l * 32 + q);
            float z0 = g4.x + e4.x, z1 = g4.y + e4.y, z2 = g4.z + e4.z, z3 = g4.w + e4.w;
            z0 = fmaxf(z0, SLOPE * z0); z1 = fmaxf(z1, SLOPE * z1);
            z2 = fmaxf(z2, SLOPE * z2); z3 = fmaxf(z3, SLOPE * z3);
            acc[q >> 2] += a4.x * z0 + a4.y * z1 + a4.z * z2 + a4.w * z3;
        }
#pragma unroll
        for (int hh = 0; hh < 8; hh++) s_pe[hh * 212 + t] = acc[hh];
    }
    __syncthreads();
    // phase 2: per-head softmax (threads 0..127)
    if (t < 128) {
        int hh = t >> 4, l16 = t & 15;
        float vals[13]; float mx = -1e30f;
#pragma unroll
        for (int k = 0; k < 13; k++) {
            int i = l16 + 16 * k;
            vals[k] = (i < NN) ? s_pe[hh * 212 + i] : -1e30f;
            mx = fmaxf(mx, vals[k]);
        }
        mx = fmaxf(mx, __shfl_xor(mx, 1)); mx = fmaxf(mx, __shfl_xor(mx, 2));
        mx = fmaxf(mx, __shfl_xor(mx, 4)); mx = fmaxf(mx, __shfl_xor(mx, 8));
        float sum = 0.f;
#pragma unroll
        for (int k = 0; k < 13; k++) {
            int i = l16 + 16 * k;
            float e = (i < NN) ? __expf(vals[k] - mx) : 0.f;
            if (i < 208) s_pe[hh * 212 + i] = e;
            sum += e;
        }
        sum += __shfl_xor(sum, 1); sum += __shfl_xor(sum, 2);
        sum += __shfl_xor(sum, 4); sum += __shfl_xor(sum, 8);
        if (l16 == 0) s_inv[hh] = 1.f / sum;
    }
    __syncthreads();
    // phase 3: o[d] = sum_i e[h(d)][i] * gs[b][i][d], i-range split across seg
    {
        int hh = d >> 4;
        const float* ep = s_pe + hh * 212;
        const float* gp = gsb + d;
        float a0 = 0.f, a1 = 0.f, a2 = 0.f, a3 = 0.f;
        int i = seg * 104;
        int iend = seg ? NN : 104;
        for (; i + 8 <= iend; i += 8) {
            float g0 = gp[(i+0)*DD], g1 = gp[(i+1)*DD], g2 = gp[(i+2)*DD], g3 = gp[(i+3)*DD];
            float g4 = gp[(i+4)*DD], g5 = gp[(i+5)*DD], g6 = gp[(i+6)*DD], g7 = gp[(i+7)*DD];
            a0 = fmaf(ep[i+0], g0, a0); a1 = fmaf(ep[i+1], g1, a1);
            a2 = fmaf(ep[i+2], g2, a2); a3 = fmaf(ep[i+3], g3, a3);
            a0 = fmaf(ep[i+4], g4, a0); a1 = fmaf(ep[i+5], g5, a1);
            a2 = fmaf(ep[i+6], g6, a2); a3 = fmaf(ep[i+7], g7, a3);
        }
        for (; i < iend; i++) a0 = fmaf(ep[i], gp[i * DD], a0);
        float part = a0 + a1 + a2 + a3;
        if (seg) s_part[d] = part;
        __syncthreads();
        if (!seg) o[(size_t)r * DD + d] = (part + s_part[d]) * s_inv[hh] + ldin<BF>(cb, l * DD + d);
    }
}
__global__ void __launch_bounds__(256, 8)
k_attn(const unsigned* bits, int l, const float* gs, const float* gd, const float* et,
       const float* gs_t4, const int* cat, const void* att, const void* cb,
       float* o) {
    __shared__ __align__(16) float smem[ATTN_SMEM];
    if (bits[0] == BFBITS) attn_body<true>(smem, l, gs, gd, et, gs_t4, cat, att, cb, o);
    else                   attn_body<false>(smem, l, gs, gd, et, gs_t4, cat, att, cb, o);
}

extern "C" void kernel_launch(void* const* d_in, const int* in_sizes, int n_in,
                              void* d_out, int out_size, void* d_ws, size_t ws_size,
                              hipStream_t stream) {
    const void* x     = d_in[0];
    const int*  cat   = (const int*)d_in[1];
    const void* emb   = d_in[2];
    const void* in1W  = d_in[3];
    const void* in1b  = d_in[4];
    const void* ln1g  = d_in[5];
    const void* ln1b  = d_in[6];
    const void* in2W  = d_in[7];
    const void* in2b  = d_in[8];
    const void* ln2g  = d_in[9];
    const void* ln2b  = d_in[10];
    const void* Wl    = d_in[11];
    const void* bl    = d_in[12];
    const void* Wr    = d_in[13];
    const void* br    = d_in[14];
    const void* We    = d_in[15];
    const void* att   = d_in[16];
    const void* cb    = d_in[17];
    const void* pW    = d_in[18];
    const void* pb    = d_in[19];
    const void* lng   = d_in[20];
    const void* lnb   = d_in[21];
    const void* oW    = d_in[22];
    const void* ob    = d_in[23];

    const unsigned* bits = (const unsigned*)ln1g;

    float* ws  = (float*)d_ws;
    float* h     = ws + 16;
    float* gs    = h    + ROWS * DD;
    float* gd    = gs   + ROWS * DD;
    float* o     = gd   + ROWS * DD;
    float* et    = o    + ROWS * DD;     // L*12*DD
    float* gs_t4 = et   + LL * 12 * DD;  // BB*GT4B
    float* wt    = gs_t4 + (size_t)BB * GT4B;  // 13*WTM

    k_wt<<<13 * 128, 128, 0, stream>>>(bits, in2W, pW, Wl, Wr, wt);
    k_et<<<LL * 12, DD, 0, stream>>>(bits, emb, We, et);
    // fused: mlp1 -> input-MLP linear2 + LN -> h, plus layer-0 gs/gd/gs_t4
    k_linG<<<LBLK, 256, 0, stream>>>(bits, 1, 0, 1, (const float*)nullptr,
                                     x, in1W, in1b, ln1g, ln1b,
                                     wt, 0, in2b, ln2g, ln2b, 0,
                                     5, 9, bl, br, 0,
                                     h, gs, gd, gs_t4, oW, ob, d_out);
    for (int l = 0; l < LL; l++) {
        k_attn<<<ROWS, 256, 0, stream>>>(bits, l, gs, gd, et, gs_t4, cat, att, cb, o);
        k_linG<<<LBLK, 256, 0, stream>>>(bits, 0, 1, (l < LL - 1) ? 1 : 0, o,
                                         x, in1W, in1b, ln1g, ln1b,
                                         wt, 1 + l, pb, lng, lnb, l * DD,
                                         5 + (l + 1), 9 + (l + 1), bl, br, (l + 1) * DD,
                                         h, gs, gd, gs_t4, oW, ob, d_out);
    }
}

// Round 18
// 313.879 us; speedup vs baseline: 1.0664x; 1.0195x over previous
//
#include <hip/hip_runtime.h>
#include <hip/hip_bf16.h>

#define NN 207
#define DD 128
#define LL 4
#define BB 16
#define ROWS (BB*NN)   // 3312
#define RB 4           // rows per linG block
#define LBLK (ROWS/RB) // 828
#define EPSV 1e-5f
#define SLOPE 0.2f
#define GT4B (32*208*4) // floats per batch in packed-transposed gs
#define WTM  16384      // floats per transposed weight matrix

#define BFBITS 0x3F803F80u

// ---------- dtype-flexible load ----------
template<bool BF>
__device__ __forceinline__ float ldin(const void* p, int i) {
    if (BF) {
        unsigned short u = ((const unsigned short*)p)[i];
        return __uint_as_float(((unsigned)u) << 16);
    } else {
        return ((const float*)p)[i];
    }
}

// load float4 worth (4 elems) at float4-index q from a (possibly bf16) array
template<bool BF>
__device__ __forceinline__ float4 ld4(const void* p, int q4) {
    if (BF) {
        uint2 u = ((const uint2*)p)[q4];
        float4 r;
        r.x = __uint_as_float(u.x << 16);
        r.y = __uint_as_float(u.x & 0xFFFF0000u);
        r.z = __uint_as_float(u.y << 16);
        r.w = __uint_as_float(u.y & 0xFFFF0000u);
        return r;
    } else {
        return ((const float4*)p)[q4];
    }
}

// dot of one weight row with sh[0..127] (et part only)
template<bool BF>
__device__ __forceinline__ float rowdot(const void* W, int rowbase, const float* sh) {
    float acc = 0.f;
    if (BF) {
        const uint4* p = (const uint4*)((const unsigned short*)W + rowbase);
#pragma unroll
        for (int q = 0; q < DD / 8; q++) {
            uint4 u = p[q];
            const float* s = sh + q * 8;
            acc += __uint_as_float(u.x << 16)        * s[0];
            acc += __uint_as_float(u.x & 0xFFFF0000u) * s[1];
            acc += __uint_as_float(u.y << 16)        * s[2];
            acc += __uint_as_float(u.y & 0xFFFF0000u) * s[3];
            acc += __uint_as_float(u.z << 16)        * s[4];
            acc += __uint_as_float(u.z & 0xFFFF0000u) * s[5];
            acc += __uint_as_float(u.w << 16)        * s[6];
            acc += __uint_as_float(u.w & 0xFFFF0000u) * s[7];
        }
    } else {
        const float4* p = (const float4*)((const float*)W + rowbase);
#pragma unroll
        for (int q = 0; q < DD / 4; q++) {
            float4 u = p[q];
            const float* s = sh + q * 4;
            acc += u.x * s[0]; acc += u.y * s[1]; acc += u.z * s[2]; acc += u.w * s[3];
        }
    }
    return acc;
}

// ---------- merged prolog: weight transpose (blocks 0..13*128-1) + edge tables ----------
// wt m: 0 = in2W; 1..4 = pW[l]; 5..8 = Wl[l]; 9..12 = Wr[l]
template<bool BF>
__device__ void pre_body(float* sh, const void* in2W, const void* pW, const void* Wl,
                         const void* Wr, const void* emb, const void* We,
                         float* wt, float* et) {
    int blk = blockIdx.x, d = threadIdx.x;
    if (blk < 13 * 128) {
        int m = blk >> 7, k = blk & 127;
        const void* src; int off;
        if (m == 0)      { src = in2W; off = 0; }
        else if (m <= 4) { src = pW;  off = (m - 1) * WTM; }
        else if (m <= 8) { src = Wl;  off = (m - 5) * WTM; }
        else             { src = Wr;  off = (m - 9) * WTM; }
        wt[m * WTM + k * DD + d] = ldin<BF>(src, off + d * DD + k);
    } else {
        int q = blk - 13 * 128;
        int l = q / 12, c = q % 12;
        sh[d] = ldin<BF>(emb, c * DD + d);
        __syncthreads();
        et[(l * 12 + c) * DD + d] = rowdot<BF>(We, l * DD * DD + d * DD, sh);
    }
}
__global__ void k_pre(const unsigned* bits, const void* in2W, const void* pW,
                      const void* Wl, const void* Wr, const void* emb, const void* We,
                      float* wt, float* et) {
    __shared__ __align__(16) float smem[DD];
    if (bits[0] == BFBITS) pre_body<true>(smem, in2W, pW, Wl, Wr, emb, We, wt, et);
    else                   pre_body<false>(smem, in2W, pW, Wl, Wr, emb, We, wt, et);
}

// ---------- fused: [optional mlp1] -> linear + LN (+ReLU+res) -> h,
//            then next gs/gd/gs_t4 OR output head.  RB=4 rows/block. ----------
// smem: sh[RB*DD] | so[RB*132] | stats[8] | s_gs[RB*128] (s_x aliases s_gs)
#define LING_SMEM (RB*DD + RB*132 + 8 + RB*DD)
template<bool BF>
__device__ void linG_body(float* smem, int hasPre, int epi, int hasNext,
                          const float* __restrict__ in,
                          const void* xin, const void* W1, const void* b1,
                          const void* g1, const void* bv1,
                          const float* __restrict__ wt, int mA,
                          const void* bias, const void* g, const void* bv, int dOff,
                          int mL, int mR, const void* bl, const void* br, int nbOff,
                          float* __restrict__ h, float* __restrict__ gs,
                          float* __restrict__ gd, float* __restrict__ gs_t4,
                          const void* oW, const void* ob, void* out) {
    float* sh    = smem;                  // RB*128
    float* so    = sh + RB * DD;          // RB*132
    float* stats = so + RB * 132;         // 8
    float* s_gs  = stats + 8;             // RB*128
    float* s_x   = s_gs;
    int r0 = blockIdx.x * RB;
    int t = threadIdx.x, d = t & 127, half = t >> 7;
    int rw = t >> 6, l64 = t & 63;        // one wave per row for LN/out

    if (hasPre) {
        // ---- inline mlp1: Linear(6->128) + LN1 + ReLU -> sh ----
        if (t < RB * 6) s_x[t] = ldin<BF>(xin, r0 * 6 + t);
        __syncthreads();
        if (half == 0) {
            float w6[6];
#pragma unroll
            for (int k = 0; k < 6; k++) w6[k] = ldin<BF>(W1, d * 6 + k);
            float b0p = ldin<BF>(b1, d);
#pragma unroll
            for (int rr = 0; rr < RB; rr++) {
                float a = b0p;
#pragma unroll
                for (int k = 0; k < 6; k++) a += w6[k] * s_x[rr * 6 + k];
                so[rr * 132 + d] = a;
            }
        }
        __syncthreads();
        {
            float v0 = so[rw * 132 + l64], v1 = so[rw * 132 + l64 + 64];
            float s = v0 + v1, sq = v0 * v0 + v1 * v1;
            s += __shfl_xor(s, 1); s += __shfl_xor(s, 2); s += __shfl_xor(s, 4);
            s += __shfl_xor(s, 8); s += __shfl_xor(s, 16); s += __shfl_xor(s, 32);
            sq += __shfl_xor(sq, 1); sq += __shfl_xor(sq, 2); sq += __shfl_xor(sq, 4);
            sq += __shfl_xor(sq, 8); sq += __shfl_xor(sq, 16); sq += __shfl_xor(sq, 32);
            if (l64 == 0) {
                float mean = s * (1.f / DD);
                float var = sq * (1.f / DD) - mean * mean;
                stats[rw * 2] = mean; stats[rw * 2 + 1] = rsqrtf(var + EPSV);
            }
        }
        __syncthreads();
        float gvp = ldin<BF>(g1, d), bbp = ldin<BF>(bv1, d);
#pragma unroll
        for (int rr = 0; rr < 2; rr++) {
            int row = half * 2 + rr;
            float v = (so[row * 132 + d] - stats[row * 2]) * stats[row * 2 + 1] * gvp + bbp;
            sh[row * DD + d] = fmaxf(v, 0.f);
        }
        __syncthreads();
    } else {
        if (t < RB * 32) ((float4*)sh)[t] = ((const float4*)(in + (size_t)r0 * DD))[t];
        __syncthreads();
    }

    // ---- phase A: projection linear via transposed weights; half -> 2 rows ----
    const float* WT = wt + mA * WTM;
    float acc[2];
    float b0 = ldin<BF>(bias, dOff + d);
    acc[0] = b0; acc[1] = b0;
    {
        const float* xr = sh + half * 2 * DD;
        for (int k4 = 0; k4 < 32; k4++) {
            float4 xa = *(const float4*)(xr + 0 * DD + k4 * 4);
            float4 xb = *(const float4*)(xr + 1 * DD + k4 * 4);
            float w0 = WT[(k4 * 4 + 0) * DD + d];
            float w1 = WT[(k4 * 4 + 1) * DD + d];
            float w2 = WT[(k4 * 4 + 2) * DD + d];
            float w3 = WT[(k4 * 4 + 3) * DD + d];
            acc[0] += w0 * xa.x + w1 * xa.y + w2 * xa.z + w3 * xa.w;
            acc[1] += w0 * xb.x + w1 * xb.y + w2 * xb.z + w3 * xb.w;
        }
    }
    __syncthreads();
#pragma unroll
    for (int rr = 0; rr < 2; rr++) so[(half * 2 + rr) * 132 + d] = acc[rr];
    __syncthreads();
    // ---- LN stats (4 rows, one wave each) ----
    {
        float v0 = so[rw * 132 + l64], v1 = so[rw * 132 + l64 + 64];
        float s = v0 + v1, sq = v0 * v0 + v1 * v1;
        s += __shfl_xor(s, 1); s += __shfl_xor(s, 2); s += __shfl_xor(s, 4);
        s += __shfl_xor(s, 8); s += __shfl_xor(s, 16); s += __shfl_xor(s, 32);
        sq += __shfl_xor(sq, 1); sq += __shfl_xor(sq, 2); sq += __shfl_xor(sq, 4);
        sq += __shfl_xor(sq, 8); sq += __shfl_xor(sq, 16); sq += __shfl_xor(sq, 32);
        if (l64 == 0) {
            float mean = s * (1.f / DD);
            float var = sq * (1.f / DD) - mean * mean;
            stats[rw * 2] = mean; stats[rw * 2 + 1] = rsqrtf(var + EPSV);
        }
    }
    __syncthreads();
    // ---- epilogue: h_new -> global h AND into sh ----
    float gv = ldin<BF>(g, dOff + d), bb = ldin<BF>(bv, dOff + d);
#pragma unroll
    for (int rr = 0; rr < 2; rr++) {
        int row = half * 2 + rr;
        int rg = r0 + row;
        float v = (so[row * 132 + d] - stats[row * 2]) * stats[row * 2 + 1] * gv + bb;
        float hn;
        if (epi) hn = h[(size_t)rg * DD + d] + fmaxf(v, 0.f);
        else     hn = v;
        h[(size_t)rg * DD + d] = hn;
        sh[row * DD + d] = hn;
    }
    __syncthreads();
    if (!hasNext) {
        // ---- output head: one wave per row ----
        float h0 = sh[rw * DD + l64], h1 = sh[rw * DD + l64 + 64];
        float s0 = h0 * ldin<BF>(oW, l64) + h1 * ldin<BF>(oW, l64 + 64);
        float s1 = h0 * ldin<BF>(oW, DD + l64) + h1 * ldin<BF>(oW, DD + l64 + 64);
        s0 += __shfl_xor(s0, 1); s0 += __shfl_xor(s0, 2); s0 += __shfl_xor(s0, 4);
        s0 += __shfl_xor(s0, 8); s0 += __shfl_xor(s0, 16); s0 += __shfl_xor(s0, 32);
        s1 += __shfl_xor(s1, 1); s1 += __shfl_xor(s1, 2); s1 += __shfl_xor(s1, 4);
        s1 += __shfl_xor(s1, 8); s1 += __shfl_xor(s1, 16); s1 += __shfl_xor(s1, 32);
        if (l64 == 0) {
            int rg = r0 + rw;
            float v0 = s0 + ldin<BF>(ob, 0);
            float v1 = s1 + ldin<BF>(ob, 1);
            if (BF) {
                ((__hip_bfloat16*)out)[rg * 2 + 0] = __float2bfloat16(v0);
                ((__hip_bfloat16*)out)[rg * 2 + 1] = __float2bfloat16(v1);
            } else {
                ((float*)out)[rg * 2 + 0] = v0;
                ((float*)out)[rg * 2 + 1] = v1;
            }
        }
        return;
    }
    // ---- phase B: gs/gd for next layer via transposed weights (half -> mL/mR) ----
    {
        const float* WTm = wt + (half ? mR : mL) * WTM;
        const void* bm = half ? br : bl;
        float acc2[RB];
        float bn = ldin<BF>(bm, nbOff + d);
#pragma unroll
        for (int rr = 0; rr < RB; rr++) acc2[rr] = bn;
        for (int k4 = 0; k4 < 32; k4++) {
            float4 x0 = *(const float4*)(sh + 0 * DD + k4 * 4);
            float4 x1 = *(const float4*)(sh + 1 * DD + k4 * 4);
            float4 x2 = *(const float4*)(sh + 2 * DD + k4 * 4);
            float4 x3 = *(const float4*)(sh + 3 * DD + k4 * 4);
            float w0 = WTm[(k4 * 4 + 0) * DD + d];
            float w1 = WTm[(k4 * 4 + 1) * DD + d];
            float w2 = WTm[(k4 * 4 + 2) * DD + d];
            float w3 = WTm[(k4 * 4 + 3) * DD + d];
            acc2[0] += w0 * x0.x + w1 * x0.y + w2 * x0.z + w3 * x0.w;
            acc2[1] += w0 * x1.x + w1 * x1.y + w2 * x1.z + w3 * x1.w;
            acc2[2] += w0 * x2.x + w1 * x2.y + w2 * x2.z + w3 * x2.w;
            acc2[3] += w0 * x3.x + w1 * x3.y + w2 * x3.z + w3 * x3.w;
        }
        if (half) {
#pragma unroll
            for (int rr = 0; rr < RB; rr++) gd[(size_t)(r0 + rr) * DD + d] = acc2[rr];
        } else {
#pragma unroll
            for (int rr = 0; rr < RB; rr++) {
                gs[(size_t)(r0 + rr) * DD + d] = acc2[rr];
                s_gs[rr * DD + d] = acc2[rr];
            }
        }
    }
    __syncthreads();
    // ---- gs_t4 write via LDS transpose: t<128 -> (d4 = t>>2, iL = t&3), i-contiguous ----
    if (t < 128) {
        int d4 = t >> 2, iL = t & 3;
        int rg = r0 + iL;
        int bb2 = rg / NN, ii = rg - bb2 * NN;
        float4 v;
        v.x = s_gs[iL * DD + d4 * 4 + 0];
        v.y = s_gs[iL * DD + d4 * 4 + 1];
        v.z = s_gs[iL * DD + d4 * 4 + 2];
        v.w = s_gs[iL * DD + d4 * 4 + 3];
        ((float4*)(gs_t4 + (size_t)bb2 * GT4B))[d4 * 208 + ii] = v;
    }
}
__global__ void k_linG(const unsigned* bits, int hasPre, int epi, int hasNext,
                       const float* in,
                       const void* xin, const void* W1, const void* b1,
                       const void* g1, const void* bv1,
                       const float* wt, int mA,
                       const void* bias, const void* g, const void* bv, int dOff,
                       int mL, int mR, const void* bl, const void* br, int nbOff,
                       float* h, float* gs, float* gd, float* gs_t4,
                       const void* oW, const void* ob, void* out) {
    __shared__ __align__(16) float smem[LING_SMEM];
    if (bits[0] == BFBITS)
        linG_body<true>(smem, hasPre, epi, hasNext, in, xin, W1, b1, g1, bv1,
                        wt, mA, bias, g, bv, dOff, mL, mR, bl, br, nbOff,
                        h, gs, gd, gs_t4, oW, ob, out);
    else
        linG_body<false>(smem, hasPre, epi, hasNext, in, xin, W1, b1, g1, bv1,
                         wt, mA, bias, g, bv, dOff, mL, mR, bl, br, nbOff,
                         h, gs, gd, gs_t4, oW, ob, out);
}

// ---------- fused attention (1 target per block, 256 thr, XCD-swizzled) ----------
// smem floats: s_ge 12*132 | s_pe 8*212 | s_inv 8 | s_part 128 | s_cat 207
#define ATTN_SMEM (12*132 + 8*212 + 8 + 128 + 207)
template<bool BF>
__device__ void attn_body(float* smem, int l, const float* __restrict__ gs,
                          const float* __restrict__ gd, const float* __restrict__ et,
                          const float* __restrict__ gs_t4, const int* __restrict__ cat,
                          const void* att, const void* cb, float* __restrict__ o) {
    float* s_ge   = smem;                  // 1584
    float* s_pe   = s_ge + 12 * 132;       // 1696
    float* s_inv  = s_pe + 8 * 212;        // 8
    float* s_part = s_inv + 8;             // 128
    int*   s_cat  = (int*)(s_part + 128);  // 207
    int p = blockIdx.x;
    int r = (p & 7) * (ROWS / 8) + (p >> 3);
    int t = threadIdx.x, d = t & 127, seg = t >> 7;
    int b = r / NN, j = r - b * NN;
    for (int idx = t; idx < NN; idx += 256) s_cat[idx] = cat[idx * NN + j];
    for (int idx = t; idx < 12 * DD; idx += 256) {
        int c = idx >> 7, k = idx & 127;
        s_ge[c * 132 + k] = et[l * 12 * DD + idx] + gd[(size_t)r * DD + k];
    }
    __syncthreads();
    const float* gsb = gs + (size_t)b * NN * DD;
    // phase 1: one source per thread; att read from GLOBAL (uniform -> scalar cache)
    if (t < NN) {
        const float4* gt = ((const float4*)(gs_t4 + (size_t)b * GT4B)) + t;
        const float4* ge = (const float4*)(s_ge + s_cat[t] * 132);
        float acc[8];
#pragma unroll
        for (int hh = 0; hh < 8; hh++) acc[hh] = 0.f;
#pragma unroll
        for (int q = 0; q < 32; q++) {
            float4 g4 = gt[q * 208];
            float4 e4 = ge[q];
            float4 a4 = ld4<BF>(att, l * 32 + q);
            float z0 = g4.x + e4.x, z1 = g4.y + e4.y, z2 = g4.z + e4.z, z3 = g4.w + e4.w;
            z0 = fmaxf(z0, SLOPE * z0); z1 = fmaxf(z1, SLOPE * z1);
            z2 = fmaxf(z2, SLOPE * z2); z3 = fmaxf(z3, SLOPE * z3);
            acc[q >> 2] += a4.x * z0 + a4.y * z1 + a4.z * z2 + a4.w * z3;
        }
#pragma unroll
        for (int hh = 0; hh < 8; hh++) s_pe[hh * 212 + t] = acc[hh];
    }
    __syncthreads();
    // phase 2: per-head softmax (threads 0..127)
    if (t < 128) {
        int hh = t >> 4, l16 = t & 15;
        float vals[13]; float mx = -1e30f;
#pragma unroll
        for (int k = 0; k < 13; k++) {
            int i = l16 + 16 * k;
            vals[k] = (i < NN) ? s_pe[hh * 212 + i] : -1e30f;
            mx = fmaxf(mx, vals[k]);
        }
        mx = fmaxf(mx, __shfl_xor(mx, 1)); mx = fmaxf(mx, __shfl_xor(mx, 2));
        mx = fmaxf(mx, __shfl_xor(mx, 4)); mx = fmaxf(mx, __shfl_xor(mx, 8));
        float sum = 0.f;
#pragma unroll
        for (int k = 0; k < 13; k++) {
            int i = l16 + 16 * k;
            float e = (i < NN) ? __expf(vals[k] - mx) : 0.f;
            if (i < 208) s_pe[hh * 212 + i] = e;
            sum += e;
        }
        sum += __shfl_xor(sum, 1); sum += __shfl_xor(sum, 2);
        sum += __shfl_xor(sum, 4); sum += __shfl_xor(sum, 8);
        if (l16 == 0) s_inv[hh] = 1.f / sum;
    }
    __syncthreads();
    // phase 3: o[d] = sum_i e[h(d)][i] * gs[b][i][d], i-range split across seg
    {
        int hh = d >> 4;
        const float* ep = s_pe + hh * 212;
        const float* gp = gsb + d;
        float a0 = 0.f, a1 = 0.f, a2 = 0.f, a3 = 0.f;
        int i = seg * 104;
        int iend = seg ? NN : 104;
        for (; i + 8 <= iend; i += 8) {
            float g0 = gp[(i+0)*DD], g1 = gp[(i+1)*DD], g2 = gp[(i+2)*DD], g3 = gp[(i+3)*DD];
            float g4 = gp[(i+4)*DD], g5 = gp[(i+5)*DD], g6 = gp[(i+6)*DD], g7 = gp[(i+7)*DD];
            a0 = fmaf(ep[i+0], g0, a0); a1 = fmaf(ep[i+1], g1, a1);
            a2 = fmaf(ep[i+2], g2, a2); a3 = fmaf(ep[i+3], g3, a3);
            a0 = fmaf(ep[i+4], g4, a0); a1 = fmaf(ep[i+5], g5, a1);
            a2 = fmaf(ep[i+6], g6, a2); a3 = fmaf(ep[i+7], g7, a3);
        }
        for (; i < iend; i++) a0 = fmaf(ep[i], gp[i * DD], a0);
        float part = a0 + a1 + a2 + a3;
        if (seg) s_part[d] = part;
        __syncthreads();
        if (!seg) o[(size_t)r * DD + d] = (part + s_part[d]) * s_inv[hh] + ldin<BF>(cb, l * DD + d);
    }
}
__global__ void __launch_bounds__(256, 8)
k_attn(const unsigned* bits, int l, const float* gs, const float* gd, const float* et,
       const float* gs_t4, const int* cat, const void* att, const void* cb,
       float* o) {
    __shared__ __align__(16) float smem[ATTN_SMEM];
    if (bits[0] == BFBITS) attn_body<true>(smem, l, gs, gd, et, gs_t4, cat, att, cb, o);
    else                   attn_body<false>(smem, l, gs, gd, et, gs_t4, cat, att, cb, o);
}

extern "C" void kernel_launch(void* const* d_in, const int* in_sizes, int n_in,
                              void* d_out, int out_size, void* d_ws, size_t ws_size,
                              hipStream_t stream) {
    const void* x     = d_in[0];
    const int*  cat   = (const int*)d_in[1];
    const void* emb   = d_in[2];
    const void* in1W  = d_in[3];
    const void* in1b  = d_in[4];
    const void* ln1g  = d_in[5];
    const void* ln1b  = d_in[6];
    const void* in2W  = d_in[7];
    const void* in2b  = d_in[8];
    const void* ln2g  = d_in[9];
    const void* ln2b  = d_in[10];
    const void* Wl    = d_in[11];
    const void* bl    = d_in[12];
    const void* Wr    = d_in[13];
    const void* br    = d_in[14];
    const void* We    = d_in[15];
    const void* att   = d_in[16];
    const void* cb    = d_in[17];
    const void* pW    = d_in[18];
    const void* pb    = d_in[19];
    const void* lng   = d_in[20];
    const void* lnb   = d_in[21];
    const void* oW    = d_in[22];
    const void* ob    = d_in[23];

    const unsigned* bits = (const unsigned*)ln1g;

    float* ws  = (float*)d_ws;
    float* h     = ws + 16;
    float* gs    = h    + ROWS * DD;
    float* gd    = gs   + ROWS * DD;
    float* o     = gd   + ROWS * DD;
    float* et    = o    + ROWS * DD;     // L*12*DD
    float* gs_t4 = et   + LL * 12 * DD;  // BB*GT4B
    float* wt    = gs_t4 + (size_t)BB * GT4B;  // 13*WTM

    k_pre<<<13 * 128 + LL * 12, DD, 0, stream>>>(bits, in2W, pW, Wl, Wr, emb, We, wt, et);
    // fused: mlp1 -> input-MLP linear2 + LN -> h, plus layer-0 gs/gd/gs_t4
    k_linG<<<LBLK, 256, 0, stream>>>(bits, 1, 0, 1, (const float*)nullptr,
                                     x, in1W, in1b, ln1g, ln1b,
                                     wt, 0, in2b, ln2g, ln2b, 0,
                                     5, 9, bl, br, 0,
                                     h, gs, gd, gs_t4, oW, ob, d_out);
    for (int l = 0; l < LL; l++) {
        k_attn<<<ROWS, 256, 0, stream>>>(bits, l, gs, gd, et, gs_t4, cat, att, cb, o);
        k_linG<<<LBLK, 256, 0, stream>>>(bits, 0, 1, (l < LL - 1) ? 1 : 0, o,
                                         x, in1W, in1b, ln1g, ln1b,
                                         wt, 1 + l, pb, lng, lnb, l * DD,
                                         5 + (l + 1), 9 + (l + 1), bl, br, (l + 1) * DD,
                                         h, gs, gd, gs_t4, oW, ob, d_out);
    }
}